// Round 1
// baseline (52939.246 us; speedup 1.0000x reference)
//
#include <hip/hip_runtime.h>

#define TT 365
#define HH 64
#define NB 16      // batch elements per block
#define NTH 512    // threads per block (8 waves)

__device__ __forceinline__ float sigm(float x) {
  // 1/(1+exp(-x)) via exp2/rcp (v_exp_f32, v_rcp_f32: ~1 ulp)
  float e = __builtin_amdgcn_exp2f(-1.4426950408889634f * x);
  return __builtin_amdgcn_rcpf(1.0f + e);
}
__device__ __forceinline__ float tanh_f(float x) {
  // overflow-safe: tanh(x) = sign(x) * (1-e)/(1+e), e = exp(-2|x|)
  float ax = __builtin_fabsf(x);
  float e = __builtin_amdgcn_exp2f(-2.8853900817779268f * ax);
  float r = (1.0f - e) * __builtin_amdgcn_rcpf(1.0f + e);
  return __builtin_copysignf(r, x);
}

__global__ __launch_bounds__(NTH, 2) void lstm2_fused(
    const float* __restrict__ x,
    const float* __restrict__ w_ih0, const float* __restrict__ w_hh0,
    const float* __restrict__ b_ih0, const float* __restrict__ b_hh0,
    const float* __restrict__ w_ih1, const float* __restrict__ w_hh1,
    const float* __restrict__ b_ih1, const float* __restrict__ b_hh1,
    float* __restrict__ out)
{
  // LDS: 32768 + 2048 + 4352 + 56 floats = 156,896 B  (< 160 KiB, 1 block/CU)
  __shared__ __align__(16) float w2[32 * 1024];     // [kq=0..31][row=0..255][4]  L2 weights [w_ih1|w_hh1]
  __shared__ __align__(16) float hbuf[128 * NB];    // rows 0..63: h1[k][b]; rows 64..127: h2[k][b]
  __shared__ __align__(16) float gates[256 * 17];   // [row][b], stride 17 breaks bank conflicts
  __shared__ __align__(16) float xbuf[NB * 3 + 8];

  const int tid  = threadIdx.x;
  const int r    = tid & 255;   // gate row (0..255) -> wave-aligned gate type
  const int half = tid >> 8;    // 0/1: which 8 of the 16 batch elems

  // ---- L1 recurrent weights -> registers (64 VGPRs/thread) ----
  float w0[HH];
  #pragma unroll
  for (int q = 0; q < 16; ++q) {
    const float4 v = *(const float4*)(w_hh0 + r * HH + q * 4);
    w0[q*4+0] = v.x; w0[q*4+1] = v.y; w0[q*4+2] = v.z; w0[q*4+3] = v.w;
  }
  const float wi0 = w_ih0[r*3+0], wi1 = w_ih0[r*3+1], wi2 = w_ih0[r*3+2];
  const float bias0 = b_ih0[r] + b_hh0[r];
  const float bias1 = b_ih1[r] + b_hh1[r];

  // ---- L2 weights -> LDS, layout [kq][row][4] so the k-loop reads are one
  //      conflict-free ds_read_b128 per lane (lane i at byte 16*i) ----
  #pragma unroll
  for (int qq = 0; qq < 16; ++qq) {
    const int kq = half * 16 + qq;
    const int k  = kq * 4;
    float4 v;
    if (k < 64) v = *(const float4*)(w_ih1 + r * 64 + k);
    else        v = *(const float4*)(w_hh1 + r * 64 + (k - 64));
    *(float4*)(w2 + kq * 1024 + r * 4) = v;
  }
  for (int i = tid; i < 128 * NB; i += NTH) hbuf[i] = 0.0f;

  // combine-role assignment: thread owns (hidden cj, cj+1) x (batch cb); c-state in regs
  const int cb = tid & 15;
  const int cj = (tid >> 4) * 2;
  float c1a = 0.f, c1b = 0.f, c2a = 0.f, c2b = 0.f;

  const int bbase = blockIdx.x * NB;
  const float* xb = x + (size_t)bbase * (TT * 3);
  const float* hb = hbuf + half * 8;          // wave-uniform offset -> broadcast reads
  const bool isg = (r >= 128) && (r < 192);   // wave-uniform: waves 2,6 do tanh

  __syncthreads();

  for (int t = 0; t < TT; ++t) {
    // ---- stage x_t ----
    if (tid < NB * 3) {
      const int bl = tid / 3, cc = tid - bl * 3;
      xbuf[tid] = xb[bl * (TT * 3) + t * 3 + cc];
    }
    __syncthreads();  // A: x ready (also h2 from prev step long since ready)

    // ---- layer-1 gates: acc[b] = bias0 + w_ih0 . x_t[b] + w_hh0_row . h1 ----
    float acc[8];
    {
      const float* xp = xbuf + half * 24;
      #pragma unroll
      for (int i = 0; i < 8; ++i)
        acc[i] = fmaf(wi0, xp[i*3], fmaf(wi1, xp[i*3+1], fmaf(wi2, xp[i*3+2], bias0)));
    }
    #pragma unroll
    for (int k = 0; k < HH; ++k) {
      const float4 ha = *(const float4*)(hb + k * NB);
      const float4 hc = *(const float4*)(hb + k * NB + 4);
      const float w = w0[k];
      acc[0]=fmaf(w,ha.x,acc[0]); acc[1]=fmaf(w,ha.y,acc[1]);
      acc[2]=fmaf(w,ha.z,acc[2]); acc[3]=fmaf(w,ha.w,acc[3]);
      acc[4]=fmaf(w,hc.x,acc[4]); acc[5]=fmaf(w,hc.y,acc[5]);
      acc[6]=fmaf(w,hc.z,acc[6]); acc[7]=fmaf(w,hc.w,acc[7]);
    }
    #pragma unroll
    for (int i = 0; i < 8; ++i) {
      const float v = acc[i];
      gates[r * 17 + half * 8 + i] = isg ? tanh_f(v) : sigm(v);
    }
    __syncthreads();  // B: gates1 ready; old h1 fully consumed

    // ---- combine 1: c1 = f*c1 + i*g ; h1 = o*tanh(c1) ----
    {
      const int j0 = cj, j1 = cj + 1;
      const float ig0 = gates[j0*17+cb],      fg0 = gates[(64+j0)*17+cb];
      const float gg0 = gates[(128+j0)*17+cb], og0 = gates[(192+j0)*17+cb];
      const float ig1 = gates[j1*17+cb],      fg1 = gates[(64+j1)*17+cb];
      const float gg1 = gates[(128+j1)*17+cb], og1 = gates[(192+j1)*17+cb];
      c1a = fmaf(fg0, c1a, ig0 * gg0);
      c1b = fmaf(fg1, c1b, ig1 * gg1);
      hbuf[j0 * NB + cb] = og0 * tanh_f(c1a);
      hbuf[j1 * NB + cb] = og1 * tanh_f(c1b);
    }
    __syncthreads();  // C: h1_t ready

    // ---- layer-2 gates: acc[b] = bias1 + [w_ih1|w_hh1]_row . [h1_t ; h2_{t-1}] ----
    #pragma unroll
    for (int i = 0; i < 8; ++i) acc[i] = bias1;
    #pragma unroll 4
    for (int kq = 0; kq < 32; ++kq) {
      const float4 w = *(const float4*)(w2 + kq * 1024 + r * 4);
      const float* hp = hb + kq * (4 * NB);
      #pragma unroll
      for (int dk = 0; dk < 4; ++dk) {
        const float wv = dk == 0 ? w.x : dk == 1 ? w.y : dk == 2 ? w.z : w.w;
        const float4 ha = *(const float4*)(hp + dk * NB);
        const float4 hc = *(const float4*)(hp + dk * NB + 4);
        acc[0]=fmaf(wv,ha.x,acc[0]); acc[1]=fmaf(wv,ha.y,acc[1]);
        acc[2]=fmaf(wv,ha.z,acc[2]); acc[3]=fmaf(wv,ha.w,acc[3]);
        acc[4]=fmaf(wv,hc.x,acc[4]); acc[5]=fmaf(wv,hc.y,acc[5]);
        acc[6]=fmaf(wv,hc.z,acc[6]); acc[7]=fmaf(wv,hc.w,acc[7]);
      }
    }
    #pragma unroll
    for (int i = 0; i < 8; ++i) {
      const float v = acc[i];
      gates[r * 17 + half * 8 + i] = isg ? tanh_f(v) : sigm(v);
    }
    __syncthreads();  // D: gates2 ready; old h2 fully consumed

    // ---- combine 2: c2, h2; final step writes the output ----
    {
      const int j0 = cj, j1 = cj + 1;
      const float ig0 = gates[j0*17+cb],      fg0 = gates[(64+j0)*17+cb];
      const float gg0 = gates[(128+j0)*17+cb], og0 = gates[(192+j0)*17+cb];
      const float ig1 = gates[j1*17+cb],      fg1 = gates[(64+j1)*17+cb];
      const float gg1 = gates[(128+j1)*17+cb], og1 = gates[(192+j1)*17+cb];
      c2a = fmaf(fg0, c2a, ig0 * gg0);
      c2b = fmaf(fg1, c2b, ig1 * gg1);
      const float h0 = og0 * tanh_f(c2a);
      const float h1v = og1 * tanh_f(c2b);
      hbuf[(64 + j0) * NB + cb] = h0;
      hbuf[(64 + j1) * NB + cb] = h1v;
      if (t == TT - 1) {
        out[(size_t)(bbase + cb) * HH + j0] = h0;
        out[(size_t)(bbase + cb) * HH + j1] = h1v;
      }
    }
    // no trailing barrier needed: next-step readers of h2/gates are separated
    // by barrier A (and B,C) of the next iteration.
  }
}

extern "C" void kernel_launch(void* const* d_in, const int* in_sizes, int n_in,
                              void* d_out, int out_size, void* d_ws, size_t ws_size,
                              hipStream_t stream) {
  const float* x     = (const float*)d_in[0];
  const float* w_ih0 = (const float*)d_in[1];
  const float* w_hh0 = (const float*)d_in[2];
  const float* b_ih0 = (const float*)d_in[3];
  const float* b_hh0 = (const float*)d_in[4];
  const float* w_ih1 = (const float*)d_in[5];
  const float* w_hh1 = (const float*)d_in[6];
  const float* b_ih1 = (const float*)d_in[7];
  const float* b_hh1 = (const float*)d_in[8];
  float* out = (float*)d_out;

  const int B = in_sizes[0] / (TT * 3);   // 4096
  const int grid = B / NB;                // 256 blocks -> 1 per CU

  lstm2_fused<<<dim3(grid), dim3(NTH), 0, stream>>>(
      x, w_ih0, w_hh0, b_ih0, b_hh0, w_ih1, w_hh1, b_ih1, b_hh1, out);
}

// Round 2
// 4223.914 us; speedup vs baseline: 12.5332x; 12.5332x over previous
//
#include <hip/hip_runtime.h>

#define TT 365
#define HH 64
#define NB 16      // batch elements per block
#define NTH 512    // threads per block (8 waves)

__device__ __forceinline__ float sigm(float x) {
  float e = __builtin_amdgcn_exp2f(-1.4426950408889634f * x);
  return __builtin_amdgcn_rcpf(1.0f + e);
}
__device__ __forceinline__ float tanh_f(float x) {
  float ax = __builtin_fabsf(x);
  float e = __builtin_amdgcn_exp2f(-2.8853900817779268f * ax);
  float r = (1.0f - e) * __builtin_amdgcn_rcpf(1.0f + e);
  return __builtin_copysignf(r, x);
}

__global__ __launch_bounds__(NTH)
__attribute__((amdgpu_waves_per_eu(2, 2)))  // pin 2 waves/EU -> 256-VGPR budget, no spill
void lstm2_fused(
    const float* __restrict__ x,
    const float* __restrict__ w_ih0, const float* __restrict__ w_hh0,
    const float* __restrict__ b_ih0, const float* __restrict__ b_hh0,
    const float* __restrict__ w_ih1, const float* __restrict__ w_hh1,
    const float* __restrict__ b_ih1, const float* __restrict__ b_hh1,
    float* __restrict__ out)
{
  // LDS: 131072 + 8192 + 17408 + 224 = 156,896 B (< 160 KiB, 1 block/CU)
  __shared__ __align__(16) float w2[32 * 1024];     // [kq 0..31][row 0..255][4]: [w_ih1 | w_hh1]
  __shared__ __align__(16) float hbuf[128 * NB];    // rows 0..63: h1[k][b]; 64..127: h2[k][b]
  __shared__ __align__(16) float gates[256 * 17];   // [row][b], stride 17: conflict-free
  __shared__ __align__(16) float xbuf[NB * 3 + 8];

  const int tid = threadIdx.x;

  // ---- phase-L1 role: lane pair shares a row; each lane holds HALF the k-range ----
  const int rr = tid >> 1;        // row 0..255 (wave-uniform gate type: 32 rows/wave)
  const int kh = tid & 1;         // 0/1: k in [0,32) or [32,64)
  // ---- phase-L2 role (same as round 1) ----
  const int r2   = tid & 255;     // row
  const int half = tid >> 8;      // which 8 of 16 batches
  // ---- combine role ----
  const int cb = tid & 15;
  const int cj = (tid >> 4) * 2;

  // L1 recurrent weights: 32 per thread (not 64) -> no pressure cliff
  float w0h[32];
  #pragma unroll
  for (int q = 0; q < 8; ++q) {
    const float4 v = *(const float4*)(w_hh0 + rr * HH + kh * 32 + q * 4);
    w0h[q*4+0] = v.x; w0h[q*4+1] = v.y; w0h[q*4+2] = v.z; w0h[q*4+3] = v.w;
  }
  const float wi0 = w_ih0[rr*3+0], wi1 = w_ih0[rr*3+1], wi2 = w_ih0[rr*3+2];
  const float bias0 = b_ih0[rr] + b_hh0[rr];
  const float bias1 = b_ih1[r2] + b_hh1[r2];

  // L2 weights -> LDS [kq][row][4]; lane i reads byte 16*i -> conflict-free b128
  #pragma unroll
  for (int qq = 0; qq < 16; ++qq) {
    const int kq = half * 16 + qq;
    const int k  = kq * 4;
    float4 v;
    if (k < 64) v = *(const float4*)(w_ih1 + r2 * 64 + k);
    else        v = *(const float4*)(w_hh1 + r2 * 64 + (k - 64));
    *(float4*)(w2 + kq * 1024 + r2 * 4) = v;
  }
  for (int i = tid; i < 128 * NB; i += NTH) hbuf[i] = 0.0f;

  float c1a = 0.f, c1b = 0.f, c2a = 0.f, c2b = 0.f;

  const int bbase = blockIdx.x * NB;
  const float* xb  = x + (size_t)bbase * (TT * 3);
  const float* hb2 = hbuf + half * 8;            // wave-uniform -> broadcast reads
  const float* h1k = hbuf + kh * 32 * NB;        // this lane's k-half of h1
  const bool isg1 = (rr >= 128) && (rr < 192);   // wave-uniform (32 rows/wave)
  const bool isg2 = (r2 >= 128) && (r2 < 192);   // wave-uniform (64 rows/wave)

  __syncthreads();

  for (int t = 0; t < TT; ++t) {
    // ---- stage x_t ----
    if (tid < NB * 3) {
      const int bl = tid / 3, cc = tid - bl * 3;
      xbuf[tid] = xb[bl * (TT * 3) + t * 3 + cc];
    }
    __syncthreads();  // A: x ready; gates fully consumed by combine2(t-1)

    // ---- L1 partial dot: acc[b] = sum_{k in my half} w0h[k] * h1[k][b], all 16 b ----
    float acc[16];
    #pragma unroll
    for (int i = 0; i < 16; ++i) acc[i] = 0.0f;
    #pragma unroll
    for (int j = 0; j < 32; ++j) {
      const float* hp = h1k + j * NB;
      const float4 ha = *(const float4*)(hp);
      const float4 hbv = *(const float4*)(hp + 4);
      const float4 hc = *(const float4*)(hp + 8);
      const float4 hd = *(const float4*)(hp + 12);
      const float w = w0h[j];
      acc[ 0]=fmaf(w,ha.x,acc[ 0]); acc[ 1]=fmaf(w,ha.y,acc[ 1]);
      acc[ 2]=fmaf(w,ha.z,acc[ 2]); acc[ 3]=fmaf(w,ha.w,acc[ 3]);
      acc[ 4]=fmaf(w,hbv.x,acc[ 4]); acc[ 5]=fmaf(w,hbv.y,acc[ 5]);
      acc[ 6]=fmaf(w,hbv.z,acc[ 6]); acc[ 7]=fmaf(w,hbv.w,acc[ 7]);
      acc[ 8]=fmaf(w,hc.x,acc[ 8]); acc[ 9]=fmaf(w,hc.y,acc[ 9]);
      acc[10]=fmaf(w,hc.z,acc[10]); acc[11]=fmaf(w,hc.w,acc[11]);
      acc[12]=fmaf(w,hd.x,acc[12]); acc[13]=fmaf(w,hd.y,acc[13]);
      acc[14]=fmaf(w,hd.z,acc[14]); acc[15]=fmaf(w,hd.w,acc[15]);
    }
    // pair-reduce within the wave (lanes 2j <-> 2j+1), then each lane finalizes 8 b's
    #pragma unroll
    for (int i = 0; i < 16; ++i) acc[i] += __shfl_xor(acc[i], 1);
    #pragma unroll
    for (int i = 0; i < 8; ++i) {
      const int b = kh * 8 + i;
      const float* xp = xbuf + b * 3;
      float v = acc[b] + fmaf(wi0, xp[0], fmaf(wi1, xp[1], fmaf(wi2, xp[2], bias0)));
      gates[rr * 17 + b] = isg1 ? tanh_f(v) : sigm(v);
    }
    __syncthreads();  // B: gates1 ready; old h1 fully consumed

    // ---- combine 1: c1 = f*c1 + i*g ; h1 = o*tanh(c1) ----
    {
      const int j0 = cj, j1 = cj + 1;
      const float ig0 = gates[j0*17+cb],       fg0 = gates[(64+j0)*17+cb];
      const float gg0 = gates[(128+j0)*17+cb], og0 = gates[(192+j0)*17+cb];
      const float ig1 = gates[j1*17+cb],       fg1 = gates[(64+j1)*17+cb];
      const float gg1 = gates[(128+j1)*17+cb], og1 = gates[(192+j1)*17+cb];
      c1a = fmaf(fg0, c1a, ig0 * gg0);
      c1b = fmaf(fg1, c1b, ig1 * gg1);
      hbuf[j0 * NB + cb] = og0 * tanh_f(c1a);
      hbuf[j1 * NB + cb] = og1 * tanh_f(c1b);
    }
    __syncthreads();  // C: h1_t ready; gates1 consumed

    // ---- L2 gates: acc[b] = bias1 + [w_ih1|w_hh1]_row . [h1_t ; h2_{t-1}] ----
    float a2[8];
    #pragma unroll
    for (int i = 0; i < 8; ++i) a2[i] = bias1;
    #pragma unroll 4
    for (int kq = 0; kq < 32; ++kq) {
      const float4 w = *(const float4*)(w2 + kq * 1024 + r2 * 4);
      const float* hp = hb2 + kq * (4 * NB);
      #pragma unroll
      for (int dk = 0; dk < 4; ++dk) {
        const float wv = dk == 0 ? w.x : dk == 1 ? w.y : dk == 2 ? w.z : w.w;
        const float4 ha = *(const float4*)(hp + dk * NB);
        const float4 hc = *(const float4*)(hp + dk * NB + 4);
        a2[0]=fmaf(wv,ha.x,a2[0]); a2[1]=fmaf(wv,ha.y,a2[1]);
        a2[2]=fmaf(wv,ha.z,a2[2]); a2[3]=fmaf(wv,ha.w,a2[3]);
        a2[4]=fmaf(wv,hc.x,a2[4]); a2[5]=fmaf(wv,hc.y,a2[5]);
        a2[6]=fmaf(wv,hc.z,a2[6]); a2[7]=fmaf(wv,hc.w,a2[7]);
      }
    }
    #pragma unroll
    for (int i = 0; i < 8; ++i) {
      const float v = a2[i];
      gates[r2 * 17 + half * 8 + i] = isg2 ? tanh_f(v) : sigm(v);
    }
    __syncthreads();  // D: gates2 ready; old h2 fully consumed

    // ---- combine 2: c2, h2; final step writes output ----
    {
      const int j0 = cj, j1 = cj + 1;
      const float ig0 = gates[j0*17+cb],       fg0 = gates[(64+j0)*17+cb];
      const float gg0 = gates[(128+j0)*17+cb], og0 = gates[(192+j0)*17+cb];
      const float ig1 = gates[j1*17+cb],       fg1 = gates[(64+j1)*17+cb];
      const float gg1 = gates[(128+j1)*17+cb], og1 = gates[(192+j1)*17+cb];
      c2a = fmaf(fg0, c2a, ig0 * gg0);
      c2b = fmaf(fg1, c2b, ig1 * gg1);
      const float h0 = og0 * tanh_f(c2a);
      const float h1v = og1 * tanh_f(c2b);
      hbuf[(64 + j0) * NB + cb] = h0;
      hbuf[(64 + j1) * NB + cb] = h1v;
      if (t == TT - 1) {
        out[(size_t)(bbase + cb) * HH + j0] = h0;
        out[(size_t)(bbase + cb) * HH + j1] = h1v;
      }
    }
    // next-step readers of h2 are separated by barriers A..C of the next iteration
  }
}

extern "C" void kernel_launch(void* const* d_in, const int* in_sizes, int n_in,
                              void* d_out, int out_size, void* d_ws, size_t ws_size,
                              hipStream_t stream) {
  const float* x     = (const float*)d_in[0];
  const float* w_ih0 = (const float*)d_in[1];
  const float* w_hh0 = (const float*)d_in[2];
  const float* b_ih0 = (const float*)d_in[3];
  const float* b_hh0 = (const float*)d_in[4];
  const float* w_ih1 = (const float*)d_in[5];
  const float* w_hh1 = (const float*)d_in[6];
  const float* b_ih1 = (const float*)d_in[7];
  const float* b_hh1 = (const float*)d_in[8];
  float* out = (float*)d_out;

  const int B = in_sizes[0] / (TT * 3);   // 4096
  const int grid = B / NB;                // 256 blocks -> 1 per CU

  lstm2_fused<<<dim3(grid), dim3(NTH), 0, stream>>>(
      x, w_ih0, w_hh0, b_ih0, b_hh0, w_ih1, w_hh1, b_ih1, b_hh1, out);
}

// Round 3
// 884.030 us; speedup vs baseline: 59.8840x; 4.7780x over previous
//
#include <hip/hip_runtime.h>

#define TT 365
#define NB 16      // batch elements per block
#define NTH 512    // 8 waves

typedef short shortx8 __attribute__((ext_vector_type(8)));
typedef float floatx4 __attribute__((ext_vector_type(4)));

__device__ __forceinline__ float sigm(float x) {
  float e = __builtin_amdgcn_exp2f(-1.4426950408889634f * x);
  return __builtin_amdgcn_rcpf(1.0f + e);
}
__device__ __forceinline__ float tanh_f(float x) {
  float ax = __builtin_fabsf(x);
  float e = __builtin_amdgcn_exp2f(-2.8853900817779268f * ax);
  float r = (1.0f - e) * __builtin_amdgcn_rcpf(1.0f + e);
  return __builtin_copysignf(r, x);
}
__device__ __forceinline__ unsigned short f2bf(float f) {  // fp32 -> bf16 bits (RNE)
  unsigned u = __float_as_uint(f);
  return (unsigned short)((u + 0x7FFFu + ((u >> 16) & 1u)) >> 16);
}
__device__ __forceinline__ float bf2f(unsigned short b) {
  return __uint_as_float(((unsigned)b) << 16);
}

__global__ __launch_bounds__(NTH)
__attribute__((amdgpu_waves_per_eu(2, 2)))  // pin 256-VGPR budget, 2 waves/SIMD
void lstm2_mfma(
    const float* __restrict__ x,
    const float* __restrict__ w_ih0, const float* __restrict__ w_hh0,
    const float* __restrict__ b_ih0, const float* __restrict__ b_hh0,
    const float* __restrict__ w_ih1, const float* __restrict__ w_hh1,
    const float* __restrict__ b_ih1, const float* __restrict__ b_hh1,
    float* __restrict__ out)
{
  // Z: [kt 0..3][lane 0..63][8 bf16] -- B-fragment order. kt0,1 = h1; kt2,3 = h2.
  __shared__ __align__(16) unsigned short Zhi[4 * 512];
  __shared__ __align__(16) unsigned short Zlo[4 * 512];
  __shared__ __align__(16) float gates[256 * 18];   // stride 18: 2-way (free) writes
  __shared__ __align__(16) float xbuf[2][NB * 3];

  const int tid  = threadIdx.x;
  const int lane = tid & 63;
  const int wv   = tid >> 6;     // wave 0..7 owns M-tiles {2wv, 2wv+1}
  const int n15  = lane & 15;
  const int quad = lane >> 4;

  // ---- persistent register A-fragments (bf16 hi/lo split of the weights) ----
  // A-operand layout: lane holds A[m = mtile*16 + (lane&15)][k = kt*32 + quad*8 + j]
  shortx8 a1hi[2][2], a1lo[2][2];   // [tile][kt], L1: K=64
  shortx8 a2hi[2][4], a2lo[2][4];   // [tile][kt], L2: K=128 ([w_ih1 | w_hh1])
  float wi[2][4][3], bias0[2][4], bias1v[2][4];  // C-layout rows (quad*4 + r)

  #pragma unroll
  for (int tt = 0; tt < 2; ++tt) {
    const int mt   = 2 * wv + tt;
    const int arow = mt * 16 + n15;
    #pragma unroll
    for (int kt = 0; kt < 2; ++kt) {
      const float* src = w_hh0 + arow * 64 + kt * 32 + quad * 8;
      shortx8 hi, lo;
      #pragma unroll
      for (int j = 0; j < 8; ++j) {
        const float v = src[j];
        const unsigned short h = f2bf(v);
        hi[j] = (short)h;
        lo[j] = (short)f2bf(v - bf2f(h));
      }
      a1hi[tt][kt] = hi; a1lo[tt][kt] = lo;
    }
    #pragma unroll
    for (int kt = 0; kt < 4; ++kt) {
      const int k0 = kt * 32 + quad * 8;
      const float* src = (k0 < 64) ? (w_ih1 + arow * 64 + k0)
                                   : (w_hh1 + arow * 64 + (k0 - 64));
      shortx8 hi, lo;
      #pragma unroll
      for (int j = 0; j < 8; ++j) {
        const float v = src[j];
        const unsigned short h = f2bf(v);
        hi[j] = (short)h;
        lo[j] = (short)f2bf(v - bf2f(h));
      }
      a2hi[tt][kt] = hi; a2lo[tt][kt] = lo;
    }
    #pragma unroll
    for (int r = 0; r < 4; ++r) {
      const int crow = mt * 16 + quad * 4 + r;  // C/D layout row
      wi[tt][r][0] = w_ih0[crow * 3 + 0];
      wi[tt][r][1] = w_ih0[crow * 3 + 1];
      wi[tt][r][2] = w_ih0[crow * 3 + 2];
      bias0[tt][r]  = b_ih0[crow] + b_hh0[crow];
      bias1v[tt][r] = b_ih1[crow] + b_hh1[crow];
    }
  }

  for (int i = tid; i < 4 * 512; i += NTH) { Zhi[i] = 0; Zlo[i] = 0; }

  const int bbase = blockIdx.x * NB;
  if (tid < NB * 3) {
    const int b = tid / 3, c = tid - 3 * b;
    xbuf[0][tid] = x[(size_t)(bbase + b) * (TT * 3) + c];
  }

  // combine role: rows (cj, cj+1) x batch cb; c-state in registers
  const int cb = n15;
  const int cj = (tid >> 4) * 2;  // 0..62, even
  float c1a = 0.f, c1b = 0.f, c2a = 0.f, c2b = 0.f;

  const shortx8* Zh8 = (const shortx8*)Zhi;
  const shortx8* Zl8 = (const shortx8*)Zlo;
  const bool isg = ((wv >> 1) == 2);  // waves 4,5 hold the g-gate rows (tanh)

  __syncthreads();

  for (int t = 0; t < TT; ++t) {
    // prefetch x for t+1 (global load issued early, stored to xbuf in combine2)
    float xpre = 0.f;
    if (tid < NB * 3 && t + 1 < TT) {
      const int b = tid / 3, c = tid - 3 * b;
      xpre = x[(size_t)(bbase + b) * (TT * 3) + (t + 1) * 3 + c];
    }

    // ======== phase 1: L1 pre-activations = Wh0 . h1  (MFMA, 3-term split) ========
    const shortx8 bh0 = Zh8[lane],      bh1 = Zh8[64 + lane];
    const shortx8 bl0 = Zl8[lane],      bl1 = Zl8[64 + lane];
    floatx4 d[2];
    d[0] = floatx4{0.f, 0.f, 0.f, 0.f};
    d[1] = floatx4{0.f, 0.f, 0.f, 0.f};
    #pragma unroll
    for (int tt = 0; tt < 2; ++tt) {
      d[tt] = __builtin_amdgcn_mfma_f32_16x16x32_bf16(a1hi[tt][0], bh0, d[tt], 0, 0, 0);
      d[tt] = __builtin_amdgcn_mfma_f32_16x16x32_bf16(a1hi[tt][1], bh1, d[tt], 0, 0, 0);
      d[tt] = __builtin_amdgcn_mfma_f32_16x16x32_bf16(a1hi[tt][0], bl0, d[tt], 0, 0, 0);
      d[tt] = __builtin_amdgcn_mfma_f32_16x16x32_bf16(a1hi[tt][1], bl1, d[tt], 0, 0, 0);
      d[tt] = __builtin_amdgcn_mfma_f32_16x16x32_bf16(a1lo[tt][0], bh0, d[tt], 0, 0, 0);
      d[tt] = __builtin_amdgcn_mfma_f32_16x16x32_bf16(a1lo[tt][1], bh1, d[tt], 0, 0, 0);
    }
    const float xv0 = xbuf[t & 1][n15 * 3 + 0];
    const float xv1 = xbuf[t & 1][n15 * 3 + 1];
    const float xv2 = xbuf[t & 1][n15 * 3 + 2];
    #pragma unroll
    for (int tt = 0; tt < 2; ++tt) {
      #pragma unroll
      for (int r = 0; r < 4; ++r) {
        float v = d[tt][r] + fmaf(wi[tt][r][0], xv0,
                    fmaf(wi[tt][r][1], xv1, fmaf(wi[tt][r][2], xv2, bias0[tt][r])));
        v = isg ? tanh_f(v) : sigm(v);
        gates[((2 * wv + tt) * 16 + quad * 4 + r) * 18 + n15] = v;
      }
    }
    __syncthreads();  // B1: gates1 ready; Zbuf kt0,1 reads done

    // ======== combine 1 ========
    {
      const float ig0 = gates[(cj)*18 + cb],       ig1 = gates[(cj + 1)*18 + cb];
      const float fg0 = gates[(64 + cj)*18 + cb],  fg1 = gates[(65 + cj)*18 + cb];
      const float gg0 = gates[(128 + cj)*18 + cb], gg1 = gates[(129 + cj)*18 + cb];
      const float og0 = gates[(192 + cj)*18 + cb], og1 = gates[(193 + cj)*18 + cb];
      c1a = fmaf(fg0, c1a, ig0 * gg0);
      c1b = fmaf(fg1, c1b, ig1 * gg1);
      const float h0 = og0 * tanh_f(c1a);
      const float h1 = og1 * tanh_f(c1b);
      const unsigned short h0h = f2bf(h0), h1h = f2bf(h1);
      const unsigned short h0l = f2bf(h0 - bf2f(h0h)), h1l = f2bf(h1 - bf2f(h1h));
      // write h1_t into Zbuf kt = cj>>5 in B-frag order (conflict-free paired b32)
      const int di = (cj >> 5) * 256 + ((cj >> 3) & 3) * 64 + cb * 4 + ((cj & 7) >> 1);
      ((unsigned*)Zhi)[di] = (unsigned)h0h | ((unsigned)h1h << 16);
      ((unsigned*)Zlo)[di] = (unsigned)h0l | ((unsigned)h1l << 16);
    }
    __syncthreads();  // B2: h1_t in Zbuf; gates1 consumed

    // ======== phase 2: L2 pre-activations = [w_ih1|w_hh1] . [h1_t ; h2_{t-1}] ========
    shortx8 zh[4], zl[4];
    #pragma unroll
    for (int kt = 0; kt < 4; ++kt) { zh[kt] = Zh8[kt * 64 + lane]; zl[kt] = Zl8[kt * 64 + lane]; }
    floatx4 e[2];
    e[0] = floatx4{0.f, 0.f, 0.f, 0.f};
    e[1] = floatx4{0.f, 0.f, 0.f, 0.f};
    #pragma unroll
    for (int tt = 0; tt < 2; ++tt) {
      #pragma unroll
      for (int kt = 0; kt < 4; ++kt) {
        e[tt] = __builtin_amdgcn_mfma_f32_16x16x32_bf16(a2hi[tt][kt], zh[kt], e[tt], 0, 0, 0);
        e[tt] = __builtin_amdgcn_mfma_f32_16x16x32_bf16(a2hi[tt][kt], zl[kt], e[tt], 0, 0, 0);
        e[tt] = __builtin_amdgcn_mfma_f32_16x16x32_bf16(a2lo[tt][kt], zh[kt], e[tt], 0, 0, 0);
      }
    }
    #pragma unroll
    for (int tt = 0; tt < 2; ++tt) {
      #pragma unroll
      for (int r = 0; r < 4; ++r) {
        float v = e[tt][r] + bias1v[tt][r];
        v = isg ? tanh_f(v) : sigm(v);
        gates[((2 * wv + tt) * 16 + quad * 4 + r) * 18 + n15] = v;
      }
    }
    __syncthreads();  // B3: gates2 ready; Zbuf kt2,3 reads done

    // ======== combine 2 ========
    {
      const float ig0 = gates[(cj)*18 + cb],       ig1 = gates[(cj + 1)*18 + cb];
      const float fg0 = gates[(64 + cj)*18 + cb],  fg1 = gates[(65 + cj)*18 + cb];
      const float gg0 = gates[(128 + cj)*18 + cb], gg1 = gates[(129 + cj)*18 + cb];
      const float og0 = gates[(192 + cj)*18 + cb], og1 = gates[(193 + cj)*18 + cb];
      c2a = fmaf(fg0, c2a, ig0 * gg0);
      c2b = fmaf(fg1, c2b, ig1 * gg1);
      const float h0 = og0 * tanh_f(c2a);
      const float h1 = og1 * tanh_f(c2b);
      const unsigned short h0h = f2bf(h0), h1h = f2bf(h1);
      const unsigned short h0l = f2bf(h0 - bf2f(h0h)), h1l = f2bf(h1 - bf2f(h1h));
      const int di = 512 + (cj >> 5) * 256 + ((cj >> 3) & 3) * 64 + cb * 4 + ((cj & 7) >> 1);
      ((unsigned*)Zhi)[di] = (unsigned)h0h | ((unsigned)h1h << 16);
      ((unsigned*)Zlo)[di] = (unsigned)h0l | ((unsigned)h1l << 16);
      if (t == TT - 1) {
        out[(size_t)(bbase + cb) * 64 + cj]     = h0;
        out[(size_t)(bbase + cb) * 64 + cj + 1] = h1;
      }
    }
    if (tid < NB * 3 && t + 1 < TT) xbuf[(t + 1) & 1][tid] = xpre;
    __syncthreads();  // B4: gates2 consumed; xbuf(t+1) staged
  }
}

extern "C" void kernel_launch(void* const* d_in, const int* in_sizes, int n_in,
                              void* d_out, int out_size, void* d_ws, size_t ws_size,
                              hipStream_t stream) {
  const float* x     = (const float*)d_in[0];
  const float* w_ih0 = (const float*)d_in[1];
  const float* w_hh0 = (const float*)d_in[2];
  const float* b_ih0 = (const float*)d_in[3];
  const float* b_hh0 = (const float*)d_in[4];
  const float* w_ih1 = (const float*)d_in[5];
  const float* w_hh1 = (const float*)d_in[6];
  const float* b_ih1 = (const float*)d_in[7];
  const float* b_hh1 = (const float*)d_in[8];
  float* out = (float*)d_out;

  const int B = in_sizes[0] / (TT * 3);   // 4096
  const int grid = B / NB;                // 256 blocks -> 1 per CU

  lstm2_mfma<<<dim3(grid), dim3(NTH), 0, stream>>>(
      x, w_ih0, w_hh0, b_ih0, b_hh0, w_ih1, w_hh1, b_ih1, b_hh1, out);
}

// Round 4
// 640.892 us; speedup vs baseline: 82.6024x; 1.3794x over previous
//
#include <hip/hip_runtime.h>

#define TT 365
#define NB 16
#define NTH 512
#define XLEN (NB * TT * 3)   // 17520 floats = 70,080 B

typedef short shortx8 __attribute__((ext_vector_type(8)));
typedef float floatx4 __attribute__((ext_vector_type(4)));

__device__ __forceinline__ float sigm(float x) {
  float e = __builtin_amdgcn_exp2f(-1.4426950408889634f * x);
  return __builtin_amdgcn_rcpf(1.0f + e);
}
__device__ __forceinline__ float tanh_f(float x) {
  float ax = __builtin_fabsf(x);
  float e = __builtin_amdgcn_exp2f(-2.8853900817779268f * ax);
  float r = (1.0f - e) * __builtin_amdgcn_rcpf(1.0f + e);
  return __builtin_copysignf(r, x);
}
__device__ __forceinline__ unsigned short f2bf(float f) {
  unsigned u = __float_as_uint(f);
  return (unsigned short)((u + 0x7FFFu + ((u >> 16) & 1u)) >> 16);
}
__device__ __forceinline__ float bf2f(unsigned short b) {
  return __uint_as_float(((unsigned)b) << 16);
}

// Write h (hi/lo bf16 split) into B-fragment-ordered Z buffer.
// Z short-index = (ktbase + (j>>5))*512 + ((j>>3)&3)*128 + b*8 + (j&7).
// Lanes quad,quad^1 hold jj,jj^1 -> shfl-pack into one b32 (2-way banks: free).
__device__ __forceinline__ void zstore(unsigned* zh, unsigned* zl, int ktbase,
                                       int j, int n15, int quad, float h) {
  const unsigned short hb = f2bf(h);
  const unsigned short lb = f2bf(h - bf2f(hb));
  const unsigned v = (unsigned)hb | ((unsigned)lb << 16);
  const unsigned part = (unsigned)__shfl_xor((int)v, 16, 64);
  if ((quad & 1) == 0) {
    const int idx = (ktbase + (j >> 5)) * 256 + ((j >> 3) & 3) * 64 + n15 * 4 + ((j & 7) >> 1);
    zh[idx] = (v & 0xffffu) | (part << 16);           // [jj]=hi_me, [jj+1]=hi_partner
    zl[idx] = (v >> 16) | (part & 0xffff0000u);       // [jj]=lo_me, [jj+1]=lo_partner
  }
}

__global__ __launch_bounds__(NTH)
__attribute__((amdgpu_waves_per_eu(2, 2)))  // 256-VGPR budget, 2 waves/SIMD
void lstm2_mfma2(
    const float* __restrict__ x,
    const float* __restrict__ w_ih0, const float* __restrict__ w_hh0,
    const float* __restrict__ b_ih0, const float* __restrict__ b_hh0,
    const float* __restrict__ w_ih1, const float* __restrict__ w_hh1,
    const float* __restrict__ b_ih1, const float* __restrict__ b_hh1,
    float* __restrict__ out)
{
  // Z[p]: [kt 0..3][lane][8 shorts], kt0,1 = h1, kt2,3 = h2. Double-buffered.
  __shared__ __align__(16) unsigned short Zhi[2][4 * 512];
  __shared__ __align__(16) unsigned short Zlo[2][4 * 512];
  __shared__ __align__(16) float xlds[XLEN];          // whole block's x, staged once

  const int tid  = threadIdx.x;
  const int lane = tid & 63;
  const int wv   = tid >> 6;
  const int n15  = lane & 15;
  const int quad = lane >> 4;
  const int bbase = blockIdx.x * NB;

  // ---- A-fragments with ROW PERMUTATION: tile mt = 2wv+tt; tile-row p holds
  //      weight row (p&3)*64 + mt*4 + (p>>2). After MFMA, lane reg r = gate r
  //      (i,f,g,o) of hidden j = mt*4+quad -> combine is in-lane. ----
  shortx8 a1hi[2][2], a1lo[2][2];   // [tile][kt]  L1 (K=64)
  shortx8 a2hi[2][4], a2lo[2][4];   // [tile][kt]  L2 (K=128: [w_ih1|w_hh1])
  float wi[2][4][3], bias0[2][4], bias1v[2][4];

  #pragma unroll
  for (int tt = 0; tt < 2; ++tt) {
    const int mt   = 2 * wv + tt;
    const int arow = (n15 & 3) * 64 + mt * 4 + (n15 >> 2);   // A-row for this lane
    #pragma unroll
    for (int kt = 0; kt < 2; ++kt) {
      const float* src = w_hh0 + arow * 64 + kt * 32 + quad * 8;
      shortx8 hi, lo;
      #pragma unroll
      for (int jj = 0; jj < 8; ++jj) {
        const float v = src[jj];
        const unsigned short h = f2bf(v);
        hi[jj] = (short)h; lo[jj] = (short)f2bf(v - bf2f(h));
      }
      a1hi[tt][kt] = hi; a1lo[tt][kt] = lo;
    }
    #pragma unroll
    for (int kt = 0; kt < 4; ++kt) {
      const int k0 = kt * 32 + quad * 8;
      const float* src = (k0 < 64) ? (w_ih1 + arow * 64 + k0)
                                   : (w_hh1 + arow * 64 + (k0 - 64));
      shortx8 hi, lo;
      #pragma unroll
      for (int jj = 0; jj < 8; ++jj) {
        const float v = src[jj];
        const unsigned short h = f2bf(v);
        hi[jj] = (short)h; lo[jj] = (short)f2bf(v - bf2f(h));
      }
      a2hi[tt][kt] = hi; a2lo[tt][kt] = lo;
    }
    #pragma unroll
    for (int r = 0; r < 4; ++r) {
      const int crow = r * 64 + mt * 4 + quad;   // C-layout row for reg r
      wi[tt][r][0] = w_ih0[crow * 3 + 0];
      wi[tt][r][1] = w_ih0[crow * 3 + 1];
      wi[tt][r][2] = w_ih0[crow * 3 + 2];
      bias0[tt][r]  = b_ih0[crow] + b_hh0[crow];
      bias1v[tt][r] = b_ih1[crow] + b_hh1[crow];
    }
  }

  // stage x (coalesced, contiguous) + zero both Z buffers
  {
    const float* xg = x + (size_t)bbase * (TT * 3);
    for (int i = tid; i < XLEN; i += NTH) xlds[i] = xg[i];
    for (int i = tid; i < 4 * 512; i += NTH) {
      Zhi[0][i] = 0; Zhi[1][i] = 0; Zlo[0][i] = 0; Zlo[1][i] = 0;
    }
  }

  float c1[2] = {0.f, 0.f}, c2[2] = {0.f, 0.f};
  __syncthreads();

  // ---- prologue: combine1(0) from x(0) only (h1(-1)=0) -> h1(0) into Z[0] ----
  {
    const float xv0 = xlds[n15 * 1095 + 0];
    const float xv1 = xlds[n15 * 1095 + 1];
    const float xv2 = xlds[n15 * 1095 + 2];
    #pragma unroll
    for (int tt = 0; tt < 2; ++tt) {
      const int j = (2 * wv + tt) * 4 + quad;
      const float p0 = fmaf(wi[tt][0][0], xv0, fmaf(wi[tt][0][1], xv1, fmaf(wi[tt][0][2], xv2, bias0[tt][0])));
      const float p1 = fmaf(wi[tt][1][0], xv0, fmaf(wi[tt][1][1], xv1, fmaf(wi[tt][1][2], xv2, bias0[tt][1])));
      const float p2 = fmaf(wi[tt][2][0], xv0, fmaf(wi[tt][2][1], xv1, fmaf(wi[tt][2][2], xv2, bias0[tt][2])));
      const float p3 = fmaf(wi[tt][3][0], xv0, fmaf(wi[tt][3][1], xv1, fmaf(wi[tt][3][2], xv2, bias0[tt][3])));
      const float ig = sigm(p0), gg = tanh_f(p2), og = sigm(p3);
      c1[tt] = ig * gg;                       // f*0 + i*g
      const float h = og * tanh_f(c1[tt]);
      zstore((unsigned*)Zhi[0], (unsigned*)Zlo[0], 0, j, n15, quad, h);
    }
  }
  __syncthreads();

  // ---- main loop: ONE barrier per step. Z[p] holds {h1(t), h2(t-1)}. ----
  for (int t = 0; t < TT; ++t) {
    const int p = t & 1;
    const shortx8* Zh = (const shortx8*)Zhi[p];
    const shortx8* Zl = (const shortx8*)Zlo[p];
    const shortx8 bh0 = Zh[lane],       bh1 = Zh[64 + lane];
    const shortx8 bh2 = Zh[128 + lane], bh3 = Zh[192 + lane];
    const shortx8 bl0 = Zl[lane],       bl1 = Zl[64 + lane];
    const shortx8 bl2 = Zl[128 + lane], bl3 = Zl[192 + lane];
    unsigned* zhN = (unsigned*)Zhi[1 - p];
    unsigned* zlN = (unsigned*)Zlo[1 - p];

    const int t1 = (t + 1 < TT) ? (t + 1) : (TT - 1);   // clamp (t=364 value unused)
    const float xv0 = xlds[n15 * 1095 + t1 * 3 + 0];
    const float xv1 = xlds[n15 * 1095 + t1 * 3 + 1];
    const float xv2 = xlds[n15 * 1095 + t1 * 3 + 2];

    #pragma unroll
    for (int tt = 0; tt < 2; ++tt) {
      const int j = (2 * wv + tt) * 4 + quad;

      // gates2(t) = [w_ih1|w_hh1] . [h1(t); h2(t-1)]  (3-term split, 2 chains)
      floatx4 eA = {0.f, 0.f, 0.f, 0.f}, eB = {0.f, 0.f, 0.f, 0.f};
      eA = __builtin_amdgcn_mfma_f32_16x16x32_bf16(a2hi[tt][0], bh0, eA, 0, 0, 0);
      eA = __builtin_amdgcn_mfma_f32_16x16x32_bf16(a2hi[tt][1], bh1, eA, 0, 0, 0);
      eA = __builtin_amdgcn_mfma_f32_16x16x32_bf16(a2hi[tt][2], bh2, eA, 0, 0, 0);
      eA = __builtin_amdgcn_mfma_f32_16x16x32_bf16(a2hi[tt][3], bh3, eA, 0, 0, 0);
      eB = __builtin_amdgcn_mfma_f32_16x16x32_bf16(a2hi[tt][0], bl0, eB, 0, 0, 0);
      eB = __builtin_amdgcn_mfma_f32_16x16x32_bf16(a2hi[tt][1], bl1, eB, 0, 0, 0);
      eB = __builtin_amdgcn_mfma_f32_16x16x32_bf16(a2hi[tt][2], bl2, eB, 0, 0, 0);
      eB = __builtin_amdgcn_mfma_f32_16x16x32_bf16(a2hi[tt][3], bl3, eB, 0, 0, 0);
      eB = __builtin_amdgcn_mfma_f32_16x16x32_bf16(a2lo[tt][0], bh0, eB, 0, 0, 0);
      eB = __builtin_amdgcn_mfma_f32_16x16x32_bf16(a2lo[tt][1], bh1, eB, 0, 0, 0);
      eB = __builtin_amdgcn_mfma_f32_16x16x32_bf16(a2lo[tt][2], bh2, eB, 0, 0, 0);
      eB = __builtin_amdgcn_mfma_f32_16x16x32_bf16(a2lo[tt][3], bh3, eB, 0, 0, 0);

      // gates1(t+1) = w_hh0 . h1(t)
      floatx4 d = {0.f, 0.f, 0.f, 0.f};
      d = __builtin_amdgcn_mfma_f32_16x16x32_bf16(a1hi[tt][0], bh0, d, 0, 0, 0);
      d = __builtin_amdgcn_mfma_f32_16x16x32_bf16(a1hi[tt][1], bh1, d, 0, 0, 0);
      d = __builtin_amdgcn_mfma_f32_16x16x32_bf16(a1hi[tt][0], bl0, d, 0, 0, 0);
      d = __builtin_amdgcn_mfma_f32_16x16x32_bf16(a1hi[tt][1], bl1, d, 0, 0, 0);
      d = __builtin_amdgcn_mfma_f32_16x16x32_bf16(a1lo[tt][0], bh0, d, 0, 0, 0);
      d = __builtin_amdgcn_mfma_f32_16x16x32_bf16(a1lo[tt][1], bh1, d, 0, 0, 0);

      // ---- combine 2 (in-lane): c2, h2(t) -> Z[1-p] kt2,3 ----
      const float i2 = sigm(eA[0] + eB[0] + bias1v[tt][0]);
      const float f2 = sigm(eA[1] + eB[1] + bias1v[tt][1]);
      const float g2 = tanh_f(eA[2] + eB[2] + bias1v[tt][2]);
      const float o2 = sigm(eA[3] + eB[3] + bias1v[tt][3]);
      c2[tt] = fmaf(f2, c2[tt], i2 * g2);
      const float h2v = o2 * tanh_f(c2[tt]);
      zstore(zhN, zlN, 2, j, n15, quad, h2v);
      if (t == TT - 1) out[(size_t)(bbase + n15) * 64 + j] = h2v;

      // ---- combine 1 (in-lane): c1, h1(t+1) -> Z[1-p] kt0,1 ----
      const float p0 = d[0] + fmaf(wi[tt][0][0], xv0, fmaf(wi[tt][0][1], xv1, fmaf(wi[tt][0][2], xv2, bias0[tt][0])));
      const float p1 = d[1] + fmaf(wi[tt][1][0], xv0, fmaf(wi[tt][1][1], xv1, fmaf(wi[tt][1][2], xv2, bias0[tt][1])));
      const float p2 = d[2] + fmaf(wi[tt][2][0], xv0, fmaf(wi[tt][2][1], xv1, fmaf(wi[tt][2][2], xv2, bias0[tt][2])));
      const float p3 = d[3] + fmaf(wi[tt][3][0], xv0, fmaf(wi[tt][3][1], xv1, fmaf(wi[tt][3][2], xv2, bias0[tt][3])));
      const float i1 = sigm(p0), f1 = sigm(p1), g1 = tanh_f(p2), o1 = sigm(p3);
      c1[tt] = fmaf(f1, c1[tt], i1 * g1);
      const float h1v = o1 * tanh_f(c1[tt]);
      zstore(zhN, zlN, 0, j, n15, quad, h1v);
    }
    __syncthreads();   // the ONLY per-step barrier (double-buffered Z)
  }
}

extern "C" void kernel_launch(void* const* d_in, const int* in_sizes, int n_in,
                              void* d_out, int out_size, void* d_ws, size_t ws_size,
                              hipStream_t stream) {
  const float* x     = (const float*)d_in[0];
  const float* w_ih0 = (const float*)d_in[1];
  const float* w_hh0 = (const float*)d_in[2];
  const float* b_ih0 = (const float*)d_in[3];
  const float* b_hh0 = (const float*)d_in[4];
  const float* w_ih1 = (const float*)d_in[5];
  const float* w_hh1 = (const float*)d_in[6];
  const float* b_ih1 = (const float*)d_in[7];
  const float* b_hh1 = (const float*)d_in[8];
  float* out = (float*)d_out;

  const int B = in_sizes[0] / (TT * 3);   // 4096
  const int grid = B / NB;                // 256 blocks -> 1 per CU

  lstm2_mfma2<<<dim3(grid), dim3(NTH), 0, stream>>>(
      x, w_ih0, w_hh0, b_ih0, b_hh0, w_ih1, w_hh1, b_ih1, b_hh1, out);
}

// Round 5
// 534.842 us; speedup vs baseline: 98.9811x; 1.1983x over previous
//
#include <hip/hip_runtime.h>

#define TT 365
#define NB 16
#define NTH 512
#define XLEN (NB * TT * 3)   // 17520 floats

typedef short shortx8 __attribute__((ext_vector_type(8)));
typedef float floatx4 __attribute__((ext_vector_type(4)));

#define MM(A, B, C) __builtin_amdgcn_mfma_f32_16x16x32_bf16((A), (B), (C), 0, 0, 0)

__device__ __forceinline__ float sigm(float x) {
  float e = __builtin_amdgcn_exp2f(-1.4426950408889634f * x);
  return __builtin_amdgcn_rcpf(1.0f + e);
}
// tanh(x) = 2*sigmoid(2x) - 1 ; saturates correctly (exp2->0 => 1, exp2->inf => -1)
__device__ __forceinline__ float tanhv(float x) {
  float e = __builtin_amdgcn_exp2f(-2.8853900817779268f * x);
  return fmaf(2.0f, __builtin_amdgcn_rcpf(1.0f + e), -1.0f);
}
__device__ __forceinline__ unsigned short f2bf(float f) {  // RNE
  unsigned u = __float_as_uint(f);
  return (unsigned short)((u + 0x7FFFu + ((u >> 16) & 1u)) >> 16);
}
__device__ __forceinline__ float bf2f(unsigned short b) {
  return __uint_as_float(((unsigned)b) << 16);
}

// One timestep: read Z[R] = {h1(t), h2(t-1)}, write Z[W] = {h1(t+1), h2(t)}.
// All addressing thread-constant; buffers chosen at compile time by the caller.
#define STEP(ZH_R, ZL_R, ZH_W, ZL_W)                                           \
  do {                                                                         \
    const shortx8* __restrict__ Zh8 = (const shortx8*)(ZH_R);                  \
    const shortx8* __restrict__ Zl8 = (const shortx8*)(ZL_R);                  \
    const shortx8 bh0 = Zh8[lane],       bh1 = Zh8[64 + lane];                 \
    const shortx8 bh2 = Zh8[128 + lane], bh3 = Zh8[192 + lane];                \
    const shortx8 bl0 = Zl8[lane],       bl1 = Zl8[64 + lane];                 \
    const shortx8 bl2 = Zl8[128 + lane], bl3 = Zl8[192 + lane];                \
    const float xv0 = xp[0], xv1 = xp[1], xv2 = xp[2];                         \
    _Pragma("unroll")                                                          \
    for (int tt = 0; tt < 2; ++tt) {                                           \
      floatx4 e = b1v[tt];                                                     \
      e = MM(a2hi[tt][0], bh0, e); e = MM(a2hi[tt][1], bh1, e);                \
      e = MM(a2hi[tt][2], bh2, e); e = MM(a2hi[tt][3], bh3, e);                \
      e = MM(a2lo[tt][0], bh0, e); e = MM(a2lo[tt][1], bh1, e);                \
      e = MM(a2lo[tt][2], bh2, e); e = MM(a2lo[tt][3], bh3, e);                \
      e = MM(a2hi[tt][0], bl0, e); e = MM(a2hi[tt][1], bl1, e);                \
      e = MM(a2hi[tt][2], bl2, e); e = MM(a2hi[tt][3], bl3, e);                \
      floatx4 d;                                                               \
      d[0] = fmaf(wiX[tt][0], xv0, fmaf(wiY[tt][0], xv1, fmaf(wiZ[tt][0], xv2, b0v[tt][0]))); \
      d[1] = fmaf(wiX[tt][1], xv0, fmaf(wiY[tt][1], xv1, fmaf(wiZ[tt][1], xv2, b0v[tt][1]))); \
      d[2] = fmaf(wiX[tt][2], xv0, fmaf(wiY[tt][2], xv1, fmaf(wiZ[tt][2], xv2, b0v[tt][2]))); \
      d[3] = fmaf(wiX[tt][3], xv0, fmaf(wiY[tt][3], xv1, fmaf(wiZ[tt][3], xv2, b0v[tt][3]))); \
      d = MM(a1hi[tt][0], bh0, d); d = MM(a1hi[tt][1], bh1, d);                \
      d = MM(a1lo[tt][0], bh0, d); d = MM(a1lo[tt][1], bh1, d);                \
      d = MM(a1hi[tt][0], bl0, d); d = MM(a1hi[tt][1], bl1, d);                \
      const float i2 = sigm(e[0]), f2s = sigm(e[1]);                           \
      const float g2 = tanhv(e[2]), o2 = sigm(e[3]);                           \
      c2[tt] = fmaf(f2s, c2[tt], i2 * g2);                                     \
      const float h2v = o2 * tanhv(c2[tt]);                                    \
      const unsigned short h2hb = f2bf(h2v);                                   \
      (ZH_W)[sidx2[tt]] = h2hb;                                                \
      (ZL_W)[sidx2[tt]] = f2bf(h2v - bf2f(h2hb));                              \
      const float i1 = sigm(d[0]), f1s = sigm(d[1]);                           \
      const float g1 = tanhv(d[2]), o1 = sigm(d[3]);                           \
      c1[tt] = fmaf(f1s, c1[tt], i1 * g1);                                     \
      const float h1v = o1 * tanhv(c1[tt]);                                    \
      const unsigned short h1hb = f2bf(h1v);                                   \
      (ZH_W)[sidx1[tt]] = h1hb;                                                \
      (ZL_W)[sidx1[tt]] = f2bf(h1v - bf2f(h1hb));                              \
    }                                                                          \
    xp += 3;                                                                   \
    __syncthreads();                                                           \
  } while (0)

__global__ __launch_bounds__(NTH)
__attribute__((amdgpu_waves_per_eu(2, 2)))
void lstm2_mfma3(
    const float* __restrict__ x,
    const float* __restrict__ w_ih0, const float* __restrict__ w_hh0,
    const float* __restrict__ b_ih0, const float* __restrict__ b_hh0,
    const float* __restrict__ w_ih1, const float* __restrict__ w_hh1,
    const float* __restrict__ b_ih1, const float* __restrict__ b_hh1,
    float* __restrict__ out)
{
  __shared__ __align__(16) unsigned short Zhi[2][2048];   // [buf][kt 0..3][lane][8]
  __shared__ __align__(16) unsigned short Zlo[2][2048];
  __shared__ __align__(16) float xlds[XLEN];

  const int tid  = threadIdx.x;
  const int lane = tid & 63;
  const int wv   = tid >> 6;
  const int n15  = lane & 15;
  const int quad = lane >> 4;
  const int bbase = blockIdx.x * NB;

  // ---- persistent A-fragments, row-permuted so C-reg r = gate r of j = mt*4+quad ----
  shortx8 a1hi[2][2], a1lo[2][2];
  shortx8 a2hi[2][4], a2lo[2][4];
  floatx4 wiX[2], wiY[2], wiZ[2], b0v[2], b1v[2];

  #pragma unroll
  for (int tt = 0; tt < 2; ++tt) {
    const int mt   = 2 * wv + tt;
    const int arow = (n15 & 3) * 64 + mt * 4 + (n15 >> 2);
    #pragma unroll
    for (int kt = 0; kt < 2; ++kt) {
      const float* src = w_hh0 + arow * 64 + kt * 32 + quad * 8;
      shortx8 hi, lo;
      #pragma unroll
      for (int jj = 0; jj < 8; ++jj) {
        const float v = src[jj];
        const unsigned short h = f2bf(v);
        hi[jj] = (short)h; lo[jj] = (short)f2bf(v - bf2f(h));
      }
      a1hi[tt][kt] = hi; a1lo[tt][kt] = lo;
    }
    #pragma unroll
    for (int kt = 0; kt < 4; ++kt) {
      const int k0 = kt * 32 + quad * 8;
      const float* src = (k0 < 64) ? (w_ih1 + arow * 64 + k0)
                                   : (w_hh1 + arow * 64 + (k0 - 64));
      shortx8 hi, lo;
      #pragma unroll
      for (int jj = 0; jj < 8; ++jj) {
        const float v = src[jj];
        const unsigned short h = f2bf(v);
        hi[jj] = (short)h; lo[jj] = (short)f2bf(v - bf2f(h));
      }
      a2hi[tt][kt] = hi; a2lo[tt][kt] = lo;
    }
    #pragma unroll
    for (int r = 0; r < 4; ++r) {
      const int crow = r * 64 + mt * 4 + quad;
      wiX[tt][r] = w_ih0[crow * 3 + 0];
      wiY[tt][r] = w_ih0[crow * 3 + 1];
      wiZ[tt][r] = w_ih0[crow * 3 + 2];
      b0v[tt][r] = b_ih0[crow] + b_hh0[crow];
      b1v[tt][r] = b_ih1[crow] + b_hh1[crow];
    }
  }

  // per-thread Z write indices (shorts) -- constant across the whole run
  int sidx1[2], sidx2[2];
  #pragma unroll
  for (int tt = 0; tt < 2; ++tt) {
    const int j = (2 * wv + tt) * 4 + quad;
    sidx1[tt] = (j >> 5) * 512 + ((j >> 3) & 3) * 128 + n15 * 8 + (j & 7);
    sidx2[tt] = sidx1[tt] + 1024;
  }

  // stage x + zero Z
  {
    const float* xg = x + (size_t)bbase * (TT * 3);
    for (int i = tid; i < XLEN; i += NTH) xlds[i] = xg[i];
    for (int i = tid; i < 2048; i += NTH) {
      Zhi[0][i] = 0; Zhi[1][i] = 0; Zlo[0][i] = 0; Zlo[1][i] = 0;
    }
  }

  float c1[2] = {0.f, 0.f}, c2[2] = {0.f, 0.f};
  unsigned short* const Zh0 = &Zhi[0][0];
  unsigned short* const Zh1 = &Zhi[1][0];
  unsigned short* const Zl0 = &Zlo[0][0];
  unsigned short* const Zl1 = &Zlo[1][0];

  __syncthreads();

  // ---- prologue: h1(0) from x(0) only (h1(-1)=0) -> Z[0] ----
  {
    const float xv0 = xlds[n15 * 1095 + 0];
    const float xv1 = xlds[n15 * 1095 + 1];
    const float xv2 = xlds[n15 * 1095 + 2];
    #pragma unroll
    for (int tt = 0; tt < 2; ++tt) {
      const float p0 = fmaf(wiX[tt][0], xv0, fmaf(wiY[tt][0], xv1, fmaf(wiZ[tt][0], xv2, b0v[tt][0])));
      const float p2 = fmaf(wiX[tt][2], xv0, fmaf(wiY[tt][2], xv1, fmaf(wiZ[tt][2], xv2, b0v[tt][2])));
      const float p3 = fmaf(wiX[tt][3], xv0, fmaf(wiY[tt][3], xv1, fmaf(wiZ[tt][3], xv2, b0v[tt][3])));
      const float ig = sigm(p0), gg = tanhv(p2), og = sigm(p3);
      c1[tt] = ig * gg;
      const float h = og * tanhv(c1[tt]);
      const unsigned short hb_ = f2bf(h);
      Zh0[sidx1[tt]] = hb_;
      Zl0[sidx1[tt]] = f2bf(h - bf2f(hb_));
    }
  }
  __syncthreads();

  // ---- main loop: t = 0..363 as 182 hardcoded-buffer pairs, then peel t=364 ----
  const float* xp = xlds + n15 * 1095 + 3;   // x(t+1), starting at t=0
  for (int it = 0; it < 182; ++it) {
    STEP(Zh0, Zl0, Zh1, Zl1);   // even t: read Z0, write Z1
    STEP(Zh1, Zl1, Zh0, Zl0);   // odd  t: read Z1, write Z0
  }

  // ---- peel t=364: layer-2 only, write output from registers ----
  {
    const shortx8* __restrict__ Zh8 = (const shortx8*)Zh0;
    const shortx8* __restrict__ Zl8 = (const shortx8*)Zl0;
    const shortx8 bh0 = Zh8[lane],       bh1 = Zh8[64 + lane];
    const shortx8 bh2 = Zh8[128 + lane], bh3 = Zh8[192 + lane];
    const shortx8 bl0 = Zl8[lane],       bl1 = Zl8[64 + lane];
    const shortx8 bl2 = Zl8[128 + lane], bl3 = Zl8[192 + lane];
    #pragma unroll
    for (int tt = 0; tt < 2; ++tt) {
      floatx4 e = b1v[tt];
      e = MM(a2hi[tt][0], bh0, e); e = MM(a2hi[tt][1], bh1, e);
      e = MM(a2hi[tt][2], bh2, e); e = MM(a2hi[tt][3], bh3, e);
      e = MM(a2lo[tt][0], bh0, e); e = MM(a2lo[tt][1], bh1, e);
      e = MM(a2lo[tt][2], bh2, e); e = MM(a2lo[tt][3], bh3, e);
      e = MM(a2hi[tt][0], bl0, e); e = MM(a2hi[tt][1], bl1, e);
      e = MM(a2hi[tt][2], bl2, e); e = MM(a2hi[tt][3], bl3, e);
      const float i2 = sigm(e[0]), f2s = sigm(e[1]);
      const float g2 = tanhv(e[2]), o2 = sigm(e[3]);
      c2[tt] = fmaf(f2s, c2[tt], i2 * g2);
      const float h2v = o2 * tanhv(c2[tt]);
      const int j = (2 * wv + tt) * 4 + quad;
      out[(size_t)(bbase + n15) * 64 + j] = h2v;
    }
  }
}

extern "C" void kernel_launch(void* const* d_in, const int* in_sizes, int n_in,
                              void* d_out, int out_size, void* d_ws, size_t ws_size,
                              hipStream_t stream) {
  const float* x     = (const float*)d_in[0];
  const float* w_ih0 = (const float*)d_in[1];
  const float* w_hh0 = (const float*)d_in[2];
  const float* b_ih0 = (const float*)d_in[3];
  const float* b_hh0 = (const float*)d_in[4];
  const float* w_ih1 = (const float*)d_in[5];
  const float* w_hh1 = (const float*)d_in[6];
  const float* b_ih1 = (const float*)d_in[7];
  const float* b_hh1 = (const float*)d_in[8];
  float* out = (float*)d_out;

  const int B = in_sizes[0] / (TT * 3);   // 4096
  const int grid = B / NB;                // 256 blocks -> 1 per CU

  lstm2_mfma3<<<dim3(grid), dim3(NTH), 0, stream>>>(
      x, w_ih0, w_hh0, b_ih0, b_hh0, w_ih1, w_hh1, b_ih1, b_hh1, out);
}

// Round 6
// 513.021 us; speedup vs baseline: 103.1912x; 1.0425x over previous
//
#include <hip/hip_runtime.h>

#define TT 365
#define NB 16
#define NTH 512
#define XLEN (NB * TT * 3)   // 17520 floats

typedef short shortx8 __attribute__((ext_vector_type(8)));
typedef float floatx4 __attribute__((ext_vector_type(4)));

#define MM(A, B, C) __builtin_amdgcn_mfma_f32_16x16x32_bf16((A), (B), (C), 0, 0, 0)

// Pre-activations arrive PRE-SCALED by -log2e (sigmoid rows) / -2log2e (g rows).
__device__ __forceinline__ float sigm2(float y) {          // y = -1.4427*x
  return __builtin_amdgcn_rcpf(1.0f + __builtin_amdgcn_exp2f(y));
}
__device__ __forceinline__ float tanh2(float y) {          // y = -2.8854*x
  return fmaf(2.0f, __builtin_amdgcn_rcpf(1.0f + __builtin_amdgcn_exp2f(y)), -1.0f);
}
__device__ __forceinline__ float tanhc(float c) {          // unscaled cell value
  float e = __builtin_amdgcn_exp2f(-2.8853900817779268f * c);
  return fmaf(2.0f, __builtin_amdgcn_rcpf(1.0f + e), -1.0f);
}
__device__ __forceinline__ unsigned short f2bf(float f) {  // RNE (setup only)
  unsigned u = __float_as_uint(f);
  return (unsigned short)((u + 0x7FFFu + ((u >> 16) & 1u)) >> 16);
}
__device__ __forceinline__ float bf2f(unsigned short b) {
  return __uint_as_float(((unsigned)b) << 16);
}
// Truncation split: hi = high16(h) (d16_hi store, ~0 VALU), lo = exact remainder.
__device__ __forceinline__ void zwr(unsigned short* zh, unsigned short* zl, int idx, float h) {
  const unsigned u = __float_as_uint(h);
  zh[idx] = (unsigned short)(u >> 16);
  const float lo = h - __uint_as_float(u & 0xFFFF0000u);
  zl[idx] = (unsigned short)(__float_as_uint(lo) >> 16);
}

#define STEP(ZH_R, ZL_R, ZH_W, ZL_W)                                           \
  do {                                                                         \
    const shortx8* __restrict__ Zh8 = (const shortx8*)(ZH_R);                  \
    const shortx8* __restrict__ Zl8 = (const shortx8*)(ZL_R);                  \
    const shortx8 bh0 = Zh8[lane],       bh1 = Zh8[64 + lane];                 \
    const shortx8 bh2 = Zh8[128 + lane], bh3 = Zh8[192 + lane];                \
    const shortx8 bl0 = Zl8[lane],       bl1 = Zl8[64 + lane];                 \
    const shortx8 bl2 = Zl8[128 + lane], bl3 = Zl8[192 + lane];                \
    const float xv0 = xp[0], xv1 = xp[1], xv2 = xp[2];                         \
    _Pragma("unroll")                                                          \
    for (int tt = 0; tt < 2; ++tt) {                                           \
      floatx4 e = b1v[tt];                                                     \
      e = MM(a2hi[tt][0], bh0, e); e = MM(a2hi[tt][1], bh1, e);                \
      e = MM(a2hi[tt][2], bh2, e); e = MM(a2hi[tt][3], bh3, e);                \
      e = MM(a2lo[tt][0], bh0, e); e = MM(a2lo[tt][1], bh1, e);                \
      e = MM(a2lo[tt][2], bh2, e); e = MM(a2lo[tt][3], bh3, e);                \
      e = MM(a2hi[tt][0], bl0, e); e = MM(a2hi[tt][1], bl1, e);                \
      e = MM(a2hi[tt][2], bl2, e); e = MM(a2hi[tt][3], bl3, e);                \
      floatx4 d;                                                               \
      d[0] = fmaf(wiX[tt][0], xv0, fmaf(wiY[tt][0], xv1, fmaf(wiZ[tt][0], xv2, b0v[tt][0]))); \
      d[1] = fmaf(wiX[tt][1], xv0, fmaf(wiY[tt][1], xv1, fmaf(wiZ[tt][1], xv2, b0v[tt][1]))); \
      d[2] = fmaf(wiX[tt][2], xv0, fmaf(wiY[tt][2], xv1, fmaf(wiZ[tt][2], xv2, b0v[tt][2]))); \
      d[3] = fmaf(wiX[tt][3], xv0, fmaf(wiY[tt][3], xv1, fmaf(wiZ[tt][3], xv2, b0v[tt][3]))); \
      d = MM(a1hi[tt][0], bh0, d); d = MM(a1hi[tt][1], bh1, d);                \
      d = MM(a1lo[tt][0], bh0, d); d = MM(a1lo[tt][1], bh1, d);                \
      d = MM(a1hi[tt][0], bl0, d); d = MM(a1hi[tt][1], bl1, d);                \
      const float i2 = sigm2(e[0]), f2s = sigm2(e[1]);                         \
      const float g2 = tanh2(e[2]), o2 = sigm2(e[3]);                          \
      c2[tt] = fmaf(f2s, c2[tt], i2 * g2);                                     \
      const float h2v = o2 * tanhc(c2[tt]);                                    \
      zwr((ZH_W), (ZL_W), sidx2[tt], h2v);                                     \
      const float i1 = sigm2(d[0]), f1s = sigm2(d[1]);                         \
      const float g1 = tanh2(d[2]), o1 = sigm2(d[3]);                          \
      c1[tt] = fmaf(f1s, c1[tt], i1 * g1);                                     \
      const float h1v = o1 * tanhc(c1[tt]);                                    \
      zwr((ZH_W), (ZL_W), sidx1[tt], h1v);                                     \
    }                                                                          \
    xp += 3;                                                                   \
    __syncthreads();                                                           \
  } while (0)

__global__ __launch_bounds__(NTH)
__attribute__((amdgpu_waves_per_eu(2, 2)))
void lstm2_mfma4(
    const float* __restrict__ x,
    const float* __restrict__ w_ih0, const float* __restrict__ w_hh0,
    const float* __restrict__ b_ih0, const float* __restrict__ b_hh0,
    const float* __restrict__ w_ih1, const float* __restrict__ w_hh1,
    const float* __restrict__ b_ih1, const float* __restrict__ b_hh1,
    float* __restrict__ out)
{
  __shared__ __align__(16) unsigned short Zhi[2][2048];
  __shared__ __align__(16) unsigned short Zlo[2][2048];
  __shared__ __align__(16) float xlds[XLEN];

  const int tid  = threadIdx.x;
  const int lane = tid & 63;
  const int wv   = tid >> 6;
  const int n15  = lane & 15;
  const int quad = lane >> 4;
  const int bbase = blockIdx.x * NB;

  const float SS = -1.4426950408889634f;   // sigmoid rows
  const float SG = -2.8853900817779268f;   // g (tanh) rows
  const float sA = ((n15 & 3) == 2) ? SG : SS;   // this lane's A-row gate scale

  shortx8 a1hi[2][2], a1lo[2][2];
  shortx8 a2hi[2][4], a2lo[2][4];
  floatx4 wiX[2], wiY[2], wiZ[2], b0v[2], b1v[2];

  #pragma unroll
  for (int tt = 0; tt < 2; ++tt) {
    const int mt   = 2 * wv + tt;
    const int arow = (n15 & 3) * 64 + mt * 4 + (n15 >> 2);
    #pragma unroll
    for (int kt = 0; kt < 2; ++kt) {
      const float* src = w_hh0 + arow * 64 + kt * 32 + quad * 8;
      shortx8 hi, lo;
      #pragma unroll
      for (int jj = 0; jj < 8; ++jj) {
        const float v = sA * src[jj];
        const unsigned short h = f2bf(v);
        hi[jj] = (short)h; lo[jj] = (short)f2bf(v - bf2f(h));
      }
      a1hi[tt][kt] = hi; a1lo[tt][kt] = lo;
    }
    #pragma unroll
    for (int kt = 0; kt < 4; ++kt) {
      const int k0 = kt * 32 + quad * 8;
      const float* src = (k0 < 64) ? (w_ih1 + arow * 64 + k0)
                                   : (w_hh1 + arow * 64 + (k0 - 64));
      shortx8 hi, lo;
      #pragma unroll
      for (int jj = 0; jj < 8; ++jj) {
        const float v = sA * src[jj];
        const unsigned short h = f2bf(v);
        hi[jj] = (short)h; lo[jj] = (short)f2bf(v - bf2f(h));
      }
      a2hi[tt][kt] = hi; a2lo[tt][kt] = lo;
    }
    #pragma unroll
    for (int r = 0; r < 4; ++r) {
      const int crow = r * 64 + mt * 4 + quad;
      const float sC = (r == 2) ? SG : SS;
      wiX[tt][r] = sC * w_ih0[crow * 3 + 0];
      wiY[tt][r] = sC * w_ih0[crow * 3 + 1];
      wiZ[tt][r] = sC * w_ih0[crow * 3 + 2];
      b0v[tt][r] = sC * (b_ih0[crow] + b_hh0[crow]);
      b1v[tt][r] = sC * (b_ih1[crow] + b_hh1[crow]);
    }
  }

  int sidx1[2], sidx2[2];
  #pragma unroll
  for (int tt = 0; tt < 2; ++tt) {
    const int j = (2 * wv + tt) * 4 + quad;
    sidx1[tt] = (j >> 5) * 512 + ((j >> 3) & 3) * 128 + n15 * 8 + (j & 7);
    sidx2[tt] = sidx1[tt] + 1024;
  }

  {
    const float* xg = x + (size_t)bbase * (TT * 3);
    for (int i = tid; i < XLEN; i += NTH) xlds[i] = xg[i];
    for (int i = tid; i < 2048; i += NTH) {
      Zhi[0][i] = 0; Zhi[1][i] = 0; Zlo[0][i] = 0; Zlo[1][i] = 0;
    }
  }

  float c1[2] = {0.f, 0.f}, c2[2] = {0.f, 0.f};
  unsigned short* const Zh0 = &Zhi[0][0];
  unsigned short* const Zh1 = &Zhi[1][0];
  unsigned short* const Zl0 = &Zlo[0][0];
  unsigned short* const Zl1 = &Zlo[1][0];

  // desync the two waves per SIMD: odd waves run at higher priority so their
  // MFMA burst overlaps the even waves' combine-VALU phase (resync at barrier)
  if (wv & 1) __builtin_amdgcn_s_setprio(1);

  __syncthreads();

  // ---- prologue: h1(0) from x(0) only ----
  {
    const float xv0 = xlds[n15 * 1095 + 0];
    const float xv1 = xlds[n15 * 1095 + 1];
    const float xv2 = xlds[n15 * 1095 + 2];
    #pragma unroll
    for (int tt = 0; tt < 2; ++tt) {
      const float p0 = fmaf(wiX[tt][0], xv0, fmaf(wiY[tt][0], xv1, fmaf(wiZ[tt][0], xv2, b0v[tt][0])));
      const float p2 = fmaf(wiX[tt][2], xv0, fmaf(wiY[tt][2], xv1, fmaf(wiZ[tt][2], xv2, b0v[tt][2])));
      const float p3 = fmaf(wiX[tt][3], xv0, fmaf(wiY[tt][3], xv1, fmaf(wiZ[tt][3], xv2, b0v[tt][3])));
      const float ig = sigm2(p0), gg = tanh2(p2), og = sigm2(p3);
      c1[tt] = ig * gg;
      const float h = og * tanhc(c1[tt]);
      zwr(Zh0, Zl0, sidx1[tt], h);
    }
  }
  __syncthreads();

  const float* xp = xlds + n15 * 1095 + 3;
  for (int it = 0; it < 182; ++it) {
    STEP(Zh0, Zl0, Zh1, Zl1);
    STEP(Zh1, Zl1, Zh0, Zl0);
  }

  // ---- peel t=364: layer-2 only, write output ----
  {
    const shortx8* __restrict__ Zh8 = (const shortx8*)Zh0;
    const shortx8* __restrict__ Zl8 = (const shortx8*)Zl0;
    const shortx8 bh0 = Zh8[lane],       bh1 = Zh8[64 + lane];
    const shortx8 bh2 = Zh8[128 + lane], bh3 = Zh8[192 + lane];
    const shortx8 bl0 = Zl8[lane],       bl1 = Zl8[64 + lane];
    const shortx8 bl2 = Zl8[128 + lane], bl3 = Zl8[192 + lane];
    #pragma unroll
    for (int tt = 0; tt < 2; ++tt) {
      floatx4 e = b1v[tt];
      e = MM(a2hi[tt][0], bh0, e); e = MM(a2hi[tt][1], bh1, e);
      e = MM(a2hi[tt][2], bh2, e); e = MM(a2hi[tt][3], bh3, e);
      e = MM(a2lo[tt][0], bh0, e); e = MM(a2lo[tt][1], bh1, e);
      e = MM(a2lo[tt][2], bh2, e); e = MM(a2lo[tt][3], bh3, e);
      e = MM(a2hi[tt][0], bl0, e); e = MM(a2hi[tt][1], bl1, e);
      e = MM(a2hi[tt][2], bl2, e); e = MM(a2hi[tt][3], bl3, e);
      const float i2 = sigm2(e[0]), f2s = sigm2(e[1]);
      const float g2 = tanh2(e[2]), o2 = sigm2(e[3]);
      c2[tt] = fmaf(f2s, c2[tt], i2 * g2);
      const float h2v = o2 * tanhc(c2[tt]);
      const int j = (2 * wv + tt) * 4 + quad;
      out[(size_t)(bbase + n15) * 64 + j] = h2v;
    }
  }
}

extern "C" void kernel_launch(void* const* d_in, const int* in_sizes, int n_in,
                              void* d_out, int out_size, void* d_ws, size_t ws_size,
                              hipStream_t stream) {
  const float* x     = (const float*)d_in[0];
  const float* w_ih0 = (const float*)d_in[1];
  const float* w_hh0 = (const float*)d_in[2];
  const float* b_ih0 = (const float*)d_in[3];
  const float* b_hh0 = (const float*)d_in[4];
  const float* w_ih1 = (const float*)d_in[5];
  const float* w_hh1 = (const float*)d_in[6];
  const float* b_ih1 = (const float*)d_in[7];
  const float* b_hh1 = (const float*)d_in[8];
  float* out = (float*)d_out;

  const int B = in_sizes[0] / (TT * 3);   // 4096
  const int grid = B / NB;                // 256 blocks -> 1 per CU

  lstm2_mfma4<<<dim3(grid), dim3(NTH), 0, stream>>>(
      x, w_ih0, w_hh0, b_ih0, b_hh0, w_ih1, w_hh1, b_ih1, b_hh1, out);
}

// Round 7
// 414.637 us; speedup vs baseline: 127.6761x; 1.2373x over previous
//
#include <hip/hip_runtime.h>

#define TT 365
#define NB 16
#define NTH 512
#define XLEN (NB * TT * 3)   // 17520 floats

typedef _Float16 halfx8 __attribute__((ext_vector_type(8)));
typedef float floatx4 __attribute__((ext_vector_type(4)));

#define MMH(A, B, C) __builtin_amdgcn_mfma_f32_16x16x32_f16((A), (B), (C), 0, 0, 0)

#define K_LO 2.44140625e-4f   // 2^-12: un-scale for the lo-weight chain

// Pre-activations arrive PRE-SCALED by -log2e (sigmoid rows) / -2log2e (g rows).
__device__ __forceinline__ float sigm2(float y) {
  return __builtin_amdgcn_rcpf(1.0f + __builtin_amdgcn_exp2f(y));
}
__device__ __forceinline__ float tanh2(float y) {
  return fmaf(2.0f, __builtin_amdgcn_rcpf(1.0f + __builtin_amdgcn_exp2f(y)), -1.0f);
}
__device__ __forceinline__ float tanhc(float c) {   // unscaled cell value
  float e = __builtin_amdgcn_exp2f(-2.8853900817779268f * c);
  return fmaf(2.0f, __builtin_amdgcn_rcpf(1.0f + e), -1.0f);
}
__device__ __forceinline__ unsigned short h16(float v) {
  _Float16 h = (_Float16)v;                 // v_cvt_f16_f32 (RNE)
  return __builtin_bit_cast(unsigned short, h);
}

// weights -> fp16 hi + fp16 (lo * 2^12); W ~= hi + K_LO * lo  (error ~2^-23)
#define LOADFRAG(SRC, SCALE, HI, LO)                                           \
  do {                                                                         \
    _Pragma("unroll")                                                          \
    for (int jj = 0; jj < 8; ++jj) {                                           \
      const float v = (SCALE) * (SRC)[jj];                                     \
      const _Float16 hh = (_Float16)v;                                         \
      (HI)[jj] = hh;                                                           \
      (LO)[jj] = (_Float16)((v - (float)hh) * 4096.0f);                        \
    }                                                                          \
  } while (0)

// L2 half-step: e = [w_ih1|w_hh1].[h1(t);h2(t-1)] ; combine2 -> h2(t) into ZW
#define E_PHASE(ZW)                                                            \
  do {                                                                         \
    _Pragma("unroll")                                                          \
    for (int tt = 0; tt < 2; ++tt) {                                           \
      floatx4 e = b1v[tt];                                                     \
      floatx4 el = {0.f, 0.f, 0.f, 0.f};                                       \
      e  = MMH(a2h[tt][0], bh0, e);  e  = MMH(a2h[tt][1], bh1, e);             \
      e  = MMH(a2h[tt][2], bh2, e);  e  = MMH(a2h[tt][3], bh3, e);             \
      el = MMH(a2l[tt][0], bh0, el); el = MMH(a2l[tt][1], bh1, el);            \
      el = MMH(a2l[tt][2], bh2, el); el = MMH(a2l[tt][3], bh3, el);            \
      const float g0 = fmaf(K_LO, el[0], e[0]);                                \
      const float g1 = fmaf(K_LO, el[1], e[1]);                                \
      const float g2 = fmaf(K_LO, el[2], e[2]);                                \
      const float g3 = fmaf(K_LO, el[3], e[3]);                                \
      const float i2 = sigm2(g0), f2s = sigm2(g1);                             \
      const float gg = tanh2(g2), o2 = sigm2(g3);                              \
      c2[tt] = fmaf(f2s, c2[tt], i2 * gg);                                     \
      const float h2v = o2 * tanhc(c2[tt]);                                    \
      (ZW)[sidx2[tt]] = h16(h2v);                                              \
    }                                                                          \
  } while (0)

// L1 half-step: d = w_ih0.x(t+1) + b0 + w_hh0.h1(t) ; combine1 -> h1(t+1) into ZW
#define D_PHASE(ZW)                                                            \
  do {                                                                         \
    _Pragma("unroll")                                                          \
    for (int tt = 0; tt < 2; ++tt) {                                           \
      floatx4 d;                                                               \
      floatx4 dl = {0.f, 0.f, 0.f, 0.f};                                       \
      d[0] = fmaf(wiX[tt][0], xv0, fmaf(wiY[tt][0], xv1, fmaf(wiZ[tt][0], xv2, b0v[tt][0]))); \
      d[1] = fmaf(wiX[tt][1], xv0, fmaf(wiY[tt][1], xv1, fmaf(wiZ[tt][1], xv2, b0v[tt][1]))); \
      d[2] = fmaf(wiX[tt][2], xv0, fmaf(wiY[tt][2], xv1, fmaf(wiZ[tt][2], xv2, b0v[tt][2]))); \
      d[3] = fmaf(wiX[tt][3], xv0, fmaf(wiY[tt][3], xv1, fmaf(wiZ[tt][3], xv2, b0v[tt][3]))); \
      d  = MMH(a1h[tt][0], bh0, d);  d  = MMH(a1h[tt][1], bh1, d);             \
      dl = MMH(a1l[tt][0], bh0, dl); dl = MMH(a1l[tt][1], bh1, dl);            \
      const float p0 = fmaf(K_LO, dl[0], d[0]);                                \
      const float p1 = fmaf(K_LO, dl[1], d[1]);                                \
      const float p2 = fmaf(K_LO, dl[2], d[2]);                                \
      const float p3 = fmaf(K_LO, dl[3], d[3]);                                \
      const float i1 = sigm2(p0), f1s = sigm2(p1);                             \
      const float gg = tanh2(p2), o1 = sigm2(p3);                              \
      c1[tt] = fmaf(f1s, c1[tt], i1 * gg);                                     \
      const float h1v = o1 * tanhc(c1[tt]);                                    \
      (ZW)[sidx1[tt]] = h16(h1v);                                              \
    }                                                                          \
  } while (0)

// One step. Group A (waves 0-3): E then D. Group B (waves 4-7): D then E.
// SIMD k hosts waves k and k+4 -> the two co-resident waves are anti-phased:
// one's MFMA burst overlaps the other's combine VALU/transcendentals.
#define STEP(ZR, ZW)                                                           \
  do {                                                                         \
    const halfx8* __restrict__ Z8 = (const halfx8*)(ZR);                       \
    const halfx8 bh0 = Z8[lane],       bh1 = Z8[64 + lane];                    \
    const halfx8 bh2 = Z8[128 + lane], bh3 = Z8[192 + lane];                   \
    const float xv0 = xp[0], xv1 = xp[1], xv2 = xp[2];                         \
    if (grpA) { E_PHASE(ZW); D_PHASE(ZW); }                                    \
    else      { D_PHASE(ZW); E_PHASE(ZW); }                                    \
    xp += 3;                                                                   \
    __syncthreads();                                                           \
  } while (0)

__global__ __launch_bounds__(NTH)
__attribute__((amdgpu_waves_per_eu(2, 2)))
void lstm2_mfma5(
    const float* __restrict__ x,
    const float* __restrict__ w_ih0, const float* __restrict__ w_hh0,
    const float* __restrict__ b_ih0, const float* __restrict__ b_hh0,
    const float* __restrict__ w_ih1, const float* __restrict__ w_hh1,
    const float* __restrict__ b_ih1, const float* __restrict__ b_hh1,
    float* __restrict__ out)
{
  __shared__ __align__(16) unsigned short Z[2][2048];  // fp16 h: [buf][kt][lane][8]
  __shared__ __align__(16) float xlds[XLEN];

  const int tid  = threadIdx.x;
  const int lane = tid & 63;
  const int wv   = tid >> 6;
  const int n15  = lane & 15;
  const int quad = lane >> 4;
  const int bbase = blockIdx.x * NB;
  const bool grpA = ((wv >> 2) & 1) == 0;

  const float SS = -1.4426950408889634f;   // sigmoid rows
  const float SG = -2.8853900817779268f;   // g (tanh) rows
  const float sA = ((n15 & 3) == 2) ? SG : SS;

  halfx8 a1h[2][2], a1l[2][2];   // [tile][kt]  L1 (K=64)
  halfx8 a2h[2][4], a2l[2][4];   // [tile][kt]  L2 (K=128: [w_ih1|w_hh1])
  floatx4 wiX[2], wiY[2], wiZ[2], b0v[2], b1v[2];

  #pragma unroll
  for (int tt = 0; tt < 2; ++tt) {
    const int mt   = 2 * wv + tt;
    const int arow = (n15 & 3) * 64 + mt * 4 + (n15 >> 2);   // row-permuted A
    #pragma unroll
    for (int kt = 0; kt < 2; ++kt) {
      const float* src = w_hh0 + arow * 64 + kt * 32 + quad * 8;
      LOADFRAG(src, sA, a1h[tt][kt], a1l[tt][kt]);
    }
    #pragma unroll
    for (int kt = 0; kt < 4; ++kt) {
      const int k0 = kt * 32 + quad * 8;
      const float* src = (k0 < 64) ? (w_ih1 + arow * 64 + k0)
                                   : (w_hh1 + arow * 64 + (k0 - 64));
      LOADFRAG(src, sA, a2h[tt][kt], a2l[tt][kt]);
    }
    #pragma unroll
    for (int r = 0; r < 4; ++r) {
      const int crow = r * 64 + mt * 4 + quad;
      const float sC = (r == 2) ? SG : SS;
      wiX[tt][r] = sC * w_ih0[crow * 3 + 0];
      wiY[tt][r] = sC * w_ih0[crow * 3 + 1];
      wiZ[tt][r] = sC * w_ih0[crow * 3 + 2];
      b0v[tt][r] = sC * (b_ih0[crow] + b_hh0[crow]);
      b1v[tt][r] = sC * (b_ih1[crow] + b_hh1[crow]);
    }
  }

  int sidx1[2], sidx2[2];
  #pragma unroll
  for (int tt = 0; tt < 2; ++tt) {
    const int j = (2 * wv + tt) * 4 + quad;
    sidx1[tt] = (j >> 5) * 512 + ((j >> 3) & 3) * 128 + n15 * 8 + (j & 7);
    sidx2[tt] = sidx1[tt] + 1024;
  }

  {
    const float* xg = x + (size_t)bbase * (TT * 3);
    for (int i = tid; i < XLEN; i += NTH) xlds[i] = xg[i];
    for (int i = tid; i < 2048; i += NTH) { Z[0][i] = 0; Z[1][i] = 0; }
  }

  float c1[2] = {0.f, 0.f}, c2[2] = {0.f, 0.f};
  unsigned short* const Zb0 = &Z[0][0];
  unsigned short* const Zb1 = &Z[1][0];

  __syncthreads();

  // ---- prologue: h1(0) from x(0) only (h1(-1)=0, h2(-1)=0) ----
  {
    const float xv0 = xlds[n15 * 1095 + 0];
    const float xv1 = xlds[n15 * 1095 + 1];
    const float xv2 = xlds[n15 * 1095 + 2];
    #pragma unroll
    for (int tt = 0; tt < 2; ++tt) {
      const float p0 = fmaf(wiX[tt][0], xv0, fmaf(wiY[tt][0], xv1, fmaf(wiZ[tt][0], xv2, b0v[tt][0])));
      const float p2 = fmaf(wiX[tt][2], xv0, fmaf(wiY[tt][2], xv1, fmaf(wiZ[tt][2], xv2, b0v[tt][2])));
      const float p3 = fmaf(wiX[tt][3], xv0, fmaf(wiY[tt][3], xv1, fmaf(wiZ[tt][3], xv2, b0v[tt][3])));
      const float ig = sigm2(p0), gg = tanh2(p2), og = sigm2(p3);
      c1[tt] = ig * gg;
      Zb0[sidx1[tt]] = h16(og * tanhc(c1[tt]));
    }
  }
  __syncthreads();

  // ---- main loop: 182 step-pairs (t=0..363), then peel t=364 ----
  const float* xp = xlds + n15 * 1095 + 3;   // x(t+1), starting at t=0
  for (int it = 0; it < 182; ++it) {
    STEP(Zb0, Zb1);
    STEP(Zb1, Zb0);
  }

  // ---- peel t=364: L2 only, write output from registers ----
  {
    const halfx8* __restrict__ Z8 = (const halfx8*)Zb0;
    const halfx8 bh0 = Z8[lane],       bh1 = Z8[64 + lane];
    const halfx8 bh2 = Z8[128 + lane], bh3 = Z8[192 + lane];
    #pragma unroll
    for (int tt = 0; tt < 2; ++tt) {
      floatx4 e = b1v[tt];
      floatx4 el = {0.f, 0.f, 0.f, 0.f};
      e  = MMH(a2h[tt][0], bh0, e);  e  = MMH(a2h[tt][1], bh1, e);
      e  = MMH(a2h[tt][2], bh2, e);  e  = MMH(a2h[tt][3], bh3, e);
      el = MMH(a2l[tt][0], bh0, el); el = MMH(a2l[tt][1], bh1, el);
      el = MMH(a2l[tt][2], bh2, el); el = MMH(a2l[tt][3], bh3, el);
      const float g0 = fmaf(K_LO, el[0], e[0]);
      const float g1 = fmaf(K_LO, el[1], e[1]);
      const float g2 = fmaf(K_LO, el[2], e[2]);
      const float g3 = fmaf(K_LO, el[3], e[3]);
      const float i2 = sigm2(g0), f2s = sigm2(g1);
      const float gg = tanh2(g2), o2 = sigm2(g3);
      c2[tt] = fmaf(f2s, c2[tt], i2 * gg);
      const float h2v = o2 * tanhc(c2[tt]);
      const int j = (2 * wv + tt) * 4 + quad;
      out[(size_t)(bbase + n15) * 64 + j] = h2v;
    }
  }
}

extern "C" void kernel_launch(void* const* d_in, const int* in_sizes, int n_in,
                              void* d_out, int out_size, void* d_ws, size_t ws_size,
                              hipStream_t stream) {
  const float* x     = (const float*)d_in[0];
  const float* w_ih0 = (const float*)d_in[1];
  const float* w_hh0 = (const float*)d_in[2];
  const float* b_ih0 = (const float*)d_in[3];
  const float* b_hh0 = (const float*)d_in[4];
  const float* w_ih1 = (const float*)d_in[5];
  const float* w_hh1 = (const float*)d_in[6];
  const float* b_ih1 = (const float*)d_in[7];
  const float* b_hh1 = (const float*)d_in[8];
  float* out = (float*)d_out;

  const int B = in_sizes[0] / (TT * 3);   // 4096
  const int grid = B / NB;                // 256 blocks -> 1 per CU

  lstm2_mfma5<<<dim3(grid), dim3(NTH), 0, stream>>>(
      x, w_ih0, w_hh0, b_ih0, b_hh0, w_ih1, w_hh1, b_ih1, b_hh1, out);
}